// Round 1
// baseline (516.299 us; speedup 1.0000x reference)
//
#include <hip/hip_runtime.h>
#include <hip/hip_bf16.h>

#define BB 16384
#define NI 5               // 1 + NUM_NEG
#define TDIM 384
#define HID 150
#define DD 128
#define ROWS (BB * NI)      // 81920

#define RT 64               // rows per block
#define AS 36               // k-stride for 32-wide k tiles (+4 pad)
#define HS_STRIDE 164       // hidden LDS stride (160 + 4)
#define TS_STRIDE 132       // te LDS stride (128 + 4)

__device__ __forceinline__ float lrelu(float x) { return x > 0.f ? x : 0.01f * x; }
__device__ __forceinline__ float softplusf(float x) {
    // stable softplus, matches jax.nn.softplus = logaddexp(x, 0)
    return fmaxf(x, 0.f) + log1pf(expf(-fabsf(x)));
}

__global__ __launch_bounds__(256, 2)
void fused_main(const int* __restrict__ batch,
                const float* __restrict__ text,
                const float* __restrict__ user_table,
                const float* __restrict__ item_table,
                const float* __restrict__ w1,
                const float* __restrict__ b1,
                const float* __restrict__ w2,
                const float* __restrict__ b2,
                const float* __restrict__ aw1,
                const float* __restrict__ ab1,
                const float* __restrict__ aw2,
                float* __restrict__ expp,   // [ROWS][4 f][4] = {e0,e1,p_ui,p_ut}
                float* __restrict__ Sglob)  // [40 * 32] padded accumulators
{
    // LDS: Hs [64][164] | A1 [64][36] | W1s [160][36]
    // aliases: W2s [128][36] over A1(+W1s head), Ts [64][132] over Hs
    __shared__ __align__(16) float smem[RT * HS_STRIDE + RT * AS + 160 * AS];
    __shared__ float S_lds[NI * 8];

    float* Hs  = smem;
    float* A1  = smem + RT * HS_STRIDE;
    float* W1s = A1 + RT * AS;
    float* W2s = A1;
    float* Ts  = smem;

    const int t  = threadIdx.x;
    const int r0 = blockIdx.x * RT;
    const int tc = t & 31;   // col group
    const int tr = t >> 5;   // row group (0..7) -> rows tr*8 .. tr*8+7
    const int lr = t >> 3;   // staging row/col (0..31)
    const int lk = t & 7;    // staging k quad

    // ================= Phase 1: hidden = leaky(text @ w1^T + b1) =================
    // tile 64 rows x 160 cols (150 real), thread: 8 rows x 5 cols (cols tc+32j)
    float acc1[8][5];
#pragma unroll
    for (int i = 0; i < 8; ++i)
#pragma unroll
        for (int j = 0; j < 5; ++j) acc1[i][j] = 0.f;

    for (int kt = 0; kt < 12; ++kt) {
        const int k0 = kt * 32;
#pragma unroll
        for (int h = 0; h < 2; ++h) {
            const int r = lr + h * 32;
            const float4 v = *(const float4*)&text[(size_t)(r0 + r) * TDIM + k0 + lk * 4];
            *(float4*)&A1[r * AS + lk * 4] = v;
        }
#pragma unroll
        for (int h = 0; h < 5; ++h) {
            const int c = lr + h * 32;
            float4 v = make_float4(0.f, 0.f, 0.f, 0.f);
            if (c < HID) v = *(const float4*)&w1[(size_t)c * TDIM + k0 + lk * 4];
            *(float4*)&W1s[c * AS + lk * 4] = v;
        }
        __syncthreads();
#pragma unroll
        for (int k4 = 0; k4 < 8; ++k4) {
            float4 a[8], w[5];
#pragma unroll
            for (int i = 0; i < 8; ++i)
                a[i] = *(const float4*)&A1[(tr * 8 + i) * AS + k4 * 4];
#pragma unroll
            for (int j = 0; j < 5; ++j)
                w[j] = *(const float4*)&W1s[(tc + 32 * j) * AS + k4 * 4];
#pragma unroll
            for (int i = 0; i < 8; ++i)
#pragma unroll
                for (int j = 0; j < 5; ++j) {
                    acc1[i][j] = fmaf(a[i].x, w[j].x, acc1[i][j]);
                    acc1[i][j] = fmaf(a[i].y, w[j].y, acc1[i][j]);
                    acc1[i][j] = fmaf(a[i].z, w[j].z, acc1[i][j]);
                    acc1[i][j] = fmaf(a[i].w, w[j].w, acc1[i][j]);
                }
        }
        __syncthreads();
    }
    // epilogue 1 -> Hs (zeros for padded cols 150..159)
#pragma unroll
    for (int i = 0; i < 8; ++i) {
        const int r = tr * 8 + i;
#pragma unroll
        for (int j = 0; j < 5; ++j) {
            const int c = tc + 32 * j;
            float v = 0.f;
            if (c < HID) v = lrelu(acc1[i][j] + b1[c]);
            Hs[r * HS_STRIDE + c] = v;
        }
    }
    __syncthreads();

    // ================= Phase 2: te = leaky(hidden @ w2^T + b2) =================
    // tile 64 rows x 128 cols, thread: 8 rows x 4 cols (cols tc+32j)
    float acc2[8][4];
#pragma unroll
    for (int i = 0; i < 8; ++i)
#pragma unroll
        for (int j = 0; j < 4; ++j) acc2[i][j] = 0.f;

    for (int kt = 0; kt < 5; ++kt) {
        const int k0 = kt * 32;
#pragma unroll
        for (int h = 0; h < 4; ++h) {
            const int c = lr + h * 32;
            const int kb = k0 + lk * 4;
            float4 v;
            v.x = (kb + 0 < HID) ? w2[c * HID + kb + 0] : 0.f;
            v.y = (kb + 1 < HID) ? w2[c * HID + kb + 1] : 0.f;
            v.z = (kb + 2 < HID) ? w2[c * HID + kb + 2] : 0.f;
            v.w = (kb + 3 < HID) ? w2[c * HID + kb + 3] : 0.f;
            *(float4*)&W2s[c * AS + lk * 4] = v;
        }
        __syncthreads();
#pragma unroll
        for (int k4 = 0; k4 < 8; ++k4) {
            float4 a[8], w[4];
#pragma unroll
            for (int i = 0; i < 8; ++i)
                a[i] = *(const float4*)&Hs[(tr * 8 + i) * HS_STRIDE + k0 + k4 * 4];
#pragma unroll
            for (int j = 0; j < 4; ++j)
                w[j] = *(const float4*)&W2s[(tc + 32 * j) * AS + k4 * 4];
#pragma unroll
            for (int i = 0; i < 8; ++i)
#pragma unroll
                for (int j = 0; j < 4; ++j) {
                    acc2[i][j] = fmaf(a[i].x, w[j].x, acc2[i][j]);
                    acc2[i][j] = fmaf(a[i].y, w[j].y, acc2[i][j]);
                    acc2[i][j] = fmaf(a[i].z, w[j].z, acc2[i][j]);
                    acc2[i][j] = fmaf(a[i].w, w[j].w, acc2[i][j]);
                }
        }
        __syncthreads();  // also protects Hs before Ts overwrite on last iter
    }
    // epilogue 2 -> Ts (aliases Hs; all Hs reads are behind the last barrier)
#pragma unroll
    for (int i = 0; i < 8; ++i) {
        const int r = tr * 8 + i;
#pragma unroll
        for (int j = 0; j < 4; ++j) {
            const int c = tc + 32 * j;
            Ts[r * TS_STRIDE + c] = lrelu(acc2[i][j] + b2[c]);
        }
    }
    if (t < NI * 8) S_lds[t] = 0.f;
    __syncthreads();

    // ================= Phase 3: features / logits / partial softmax =================
    {
        const int row = t >> 2;       // 0..63
        const int f   = t & 3;
        const int gr  = r0 + row;
        const int b   = gr / 5;
        const int n   = gr - b * 5;
        const int uid = batch[b * 6];
        const int iid = batch[b * 6 + 1 + n];
        const float* up  = user_table + (size_t)uid * DD + f * 32;
        const float* ip  = item_table + (size_t)iid * DD + f * 32;
        const float* tp  = Ts + row * TS_STRIDE + f * 32;
        const float* a1p = aw1 + f * 2 * 96;   // [m][3*32]

        float ss = 0.f, z0 = 0.f, z1 = 0.f, sui = 0.f, sut = 0.f;
#pragma unroll
        for (int q = 0; q < 8; ++q) {
            const float4 u4 = *(const float4*)(up + q * 4);
            const float4 e4 = *(const float4*)(ip + q * 4);
            const float4 t4 = *(const float4*)(tp + q * 4);
            const float uu[4] = {u4.x, u4.y, u4.z, u4.w};
            const float ee[4] = {e4.x, e4.y, e4.z, e4.w};
            const float tt[4] = {t4.x, t4.y, t4.z, t4.w};
#pragma unroll
            for (int c = 0; c < 4; ++c) {
                const int i = q * 4 + c;
                const float u = uu[c], e = ee[c], x = tt[c];
                ss  = fmaf(u, u, ss); ss = fmaf(e, e, ss); ss = fmaf(x, x, ss);
                z0  = fmaf(u, a1p[i],       z0);
                z0  = fmaf(e, a1p[32 + i],  z0);
                z0  = fmaf(x, a1p[64 + i],  z0);
                z1  = fmaf(u, a1p[96 + i],  z1);
                z1  = fmaf(e, a1p[128 + i], z1);
                z1  = fmaf(x, a1p[160 + i], z1);
                sui = fmaf(u, e, sui);
                sut = fmaf(u, x, sut);
            }
        }
        const float inv = 1.f / fmaxf(sqrtf(ss), 1e-12f);
        const float h0 = tanhf(fmaf(z0, inv, ab1[f * 2 + 0]));
        const float h1 = tanhf(fmaf(z1, inv, ab1[f * 2 + 1]));
        const float l0 = fmaf(h0, aw2[f * 4 + 0], h1 * aw2[f * 4 + 1]);
        const float l1 = fmaf(h0, aw2[f * 4 + 2], h1 * aw2[f * 4 + 3]);
        const float e0 = expf(l0), e1 = expf(l1);
        const float pui = softplusf(sui), put = softplusf(sut);
        *(float4*)&expp[((size_t)gr * 4 + f) * 4] = make_float4(e0, e1, pui, put);
        atomicAdd(&S_lds[n * 8 + f * 2 + 0], e0);
        atomicAdd(&S_lds[n * 8 + f * 2 + 1], e1);
    }
    __syncthreads();
    if (t < NI * 8) atomicAdd(&Sglob[t * 32], S_lds[t]);
}

__global__ void finalize(const float* __restrict__ expp,
                         const float* __restrict__ Sglob,
                         float* __restrict__ out)
{
    const int gr = blockIdx.x * 256 + threadIdx.x;
    if (gr >= ROWS) return;
    const int b = gr / 5;
    const int n = gr - b * 5;
    float r = 0.f;
#pragma unroll
    for (int f = 0; f < 4; ++f) {
        const float4 v = *(const float4*)&expp[((size_t)gr * 4 + f) * 4];
        const float S0 = Sglob[(n * 8 + f * 2 + 0) * 32];
        const float S1 = Sglob[(n * 8 + f * 2 + 1) * 32];
        r += v.x / S0 * v.z + v.y / S1 * v.w;
    }
    out[gr] = r;
}

extern "C" void kernel_launch(void* const* d_in, const int* in_sizes, int n_in,
                              void* d_out, int out_size, void* d_ws, size_t ws_size,
                              hipStream_t stream)
{
    (void)in_sizes; (void)n_in; (void)out_size; (void)ws_size;
    const int*   batch      = (const int*)d_in[0];
    const float* text       = (const float*)d_in[1];
    const float* user_table = (const float*)d_in[2];
    const float* item_table = (const float*)d_in[3];
    const float* w1         = (const float*)d_in[4];
    const float* b1         = (const float*)d_in[5];
    const float* w2         = (const float*)d_in[6];
    const float* b2         = (const float*)d_in[7];
    const float* aw1        = (const float*)d_in[8];
    const float* ab1        = (const float*)d_in[9];
    const float* aw2        = (const float*)d_in[10];
    float* out  = (float*)d_out;

    float* expp  = (float*)d_ws;                  // ROWS*16 floats = 5.24 MB
    float* Sglob = expp + (size_t)ROWS * 16;      // 40*32 floats, line-padded

    hipMemsetAsync(Sglob, 0, 40 * 32 * sizeof(float), stream);
    fused_main<<<ROWS / RT, 256, 0, stream>>>(batch, text, user_table, item_table,
                                              w1, b1, w2, b2, aw1, ab1, aw2,
                                              expp, Sglob);
    finalize<<<(ROWS + 255) / 256, 256, 0, stream>>>(expp, Sglob, out);
}

// Round 2
// 380.963 us; speedup vs baseline: 1.3552x; 1.3552x over previous
//
#include <hip/hip_runtime.h>
#include <hip/hip_bf16.h>

#define BB 16384
#define NN 5                // 1 + NUM_NEG
#define TDIM 384
#define HID 150
#define DD 128
#define ROWS (BB * NN)      // 81920
#define RT 64               // rows per block

typedef __attribute__((ext_vector_type(8))) short short8;
typedef __attribute__((ext_vector_type(4))) float f32x4;

// LDS byte map (aliased phases):
//   GEMM1: As [64][40]bf16 @0 (5120) | Ws1 [160][40]bf16 @5120 (12800) | Hs [64][168]bf16 @17920 (21504)
//   GEMM2: Ws2 [128][40]bf16 @0 (10240)                               | Hs (read)
//   Phase3: Ts [64][132]f32 @0 (33792)   (Hs/staging dead by then)
#define AS_OFF   0
#define WS1_OFF  5120
#define WS2_OFF  0
#define HS_OFF   17920
#define TS_OFF   0
#define SMEM_BYTES 39424

__device__ __forceinline__ float lrelu(float x) { return x > 0.f ? x : 0.01f * x; }
__device__ __forceinline__ float softplusf(float x) {
    return fmaxf(x, 0.f) + log1pf(expf(-fabsf(x)));
}

__device__ __forceinline__ short8 pack8(const float4 a, const float4 b) {
    union { short8 s; __hip_bfloat16 h[8]; } u;
    u.h[0] = __float2bfloat16(a.x); u.h[1] = __float2bfloat16(a.y);
    u.h[2] = __float2bfloat16(a.z); u.h[3] = __float2bfloat16(a.w);
    u.h[4] = __float2bfloat16(b.x); u.h[5] = __float2bfloat16(b.y);
    u.h[6] = __float2bfloat16(b.z); u.h[7] = __float2bfloat16(b.w);
    return u.s;
}

__global__ __launch_bounds__(256, 4)
void fused_main(const int* __restrict__ batch,
                const float* __restrict__ text,
                const float* __restrict__ user_table,
                const float* __restrict__ item_table,
                const float* __restrict__ w1,
                const float* __restrict__ b1,
                const float* __restrict__ w2,
                const float* __restrict__ b2,
                const float* __restrict__ aw1,
                const float* __restrict__ ab1,
                const float* __restrict__ aw2,
                float* __restrict__ expp,   // [ROWS][4 f][4] = {e0,e1,p_ui,p_ut}
                float* __restrict__ Sglob)  // [40 * 32] padded accumulators
{
    __shared__ __align__(16) unsigned char smem[SMEM_BYTES];
    __shared__ float S_lds[40];

    __hip_bfloat16* As  = (__hip_bfloat16*)(smem + AS_OFF);
    __hip_bfloat16* Ws1 = (__hip_bfloat16*)(smem + WS1_OFF);
    __hip_bfloat16* Ws2 = (__hip_bfloat16*)(smem + WS2_OFF);
    __hip_bfloat16* Hs  = (__hip_bfloat16*)(smem + HS_OFF);
    float*          Ts  = (float*)(smem + TS_OFF);

    const int t    = threadIdx.x;
    const int r0   = blockIdx.x * RT;
    const int lane = t & 63;
    const int wv   = t >> 6;        // wave 0..3
    const int m16  = lane & 15;
    const int quad = lane >> 4;
    const int wr   = (wv & 1) * 32; // wave row offset
    const int wc   = (wv >> 1) * 80;// wave col offset (GEMM1)

    const int srow = t >> 2;        // staging row 0..63
    const int sko  = (t & 3) * 8;   // staging k-octet

    // ================= GEMM1: hidden = leaky(text @ w1^T + b1), M=64 N=160 K=384 =================
    f32x4 acc1[2][5];
#pragma unroll
    for (int i = 0; i < 2; ++i)
#pragma unroll
        for (int j = 0; j < 5; ++j) acc1[i][j] = (f32x4){0.f, 0.f, 0.f, 0.f};

    for (int kt = 0; kt < 12; ++kt) {
        const int k0 = kt * 32;
        // stage A (text) 64x32 -> bf16
        {
            const float* p = &text[(size_t)(r0 + srow) * TDIM + k0 + sko];
            const float4 ta = *(const float4*)p;
            const float4 tb = *(const float4*)(p + 4);
            *(short8*)&As[srow * 40 + sko] = pack8(ta, tb);
        }
        // stage B (w1 rows = output cols) 160x32 -> bf16, zero rows >= 150
        for (int idx = t; idx < 640; idx += 256) {
            const int row = idx >> 2;
            const int ko  = (idx & 3) * 8;
            short8 v = {0, 0, 0, 0, 0, 0, 0, 0};
            if (row < HID) {
                const float* p = &w1[(size_t)row * TDIM + k0 + ko];
                v = pack8(*(const float4*)p, *(const float4*)(p + 4));
            }
            *(short8*)&Ws1[row * 40 + ko] = v;
        }
        __syncthreads();
        const short8 a0 = *(const short8*)&As[(wr + m16) * 40 + quad * 8];
        const short8 a1 = *(const short8*)&As[(wr + 16 + m16) * 40 + quad * 8];
#pragma unroll
        for (int tj = 0; tj < 5; ++tj) {
            const short8 b = *(const short8*)&Ws1[(wc + tj * 16 + m16) * 40 + quad * 8];
            acc1[0][tj] = __builtin_amdgcn_mfma_f32_16x16x32_bf16(a0, b, acc1[0][tj], 0, 0, 0);
            acc1[1][tj] = __builtin_amdgcn_mfma_f32_16x16x32_bf16(a1, b, acc1[1][tj], 0, 0, 0);
        }
        __syncthreads();
    }
    // epilogue 1 -> Hs bf16 (C layout: col=lane&15, row=quad*4+reg)
#pragma unroll
    for (int tj = 0; tj < 5; ++tj) {
        const int col = wc + tj * 16 + m16;
        const float bv = (col < HID) ? b1[col] : 0.f;
#pragma unroll
        for (int ti = 0; ti < 2; ++ti) {
#pragma unroll
            for (int r = 0; r < 4; ++r) {
                const int row = wr + ti * 16 + quad * 4 + r;
                float v = lrelu(acc1[ti][tj][r] + bv);
                if (col >= HID) v = 0.f;
                Hs[row * 168 + col] = __float2bfloat16(v);
            }
        }
    }
    __syncthreads();

    // ================= GEMM2: te = leaky(hidden @ w2^T + b2), M=64 N=128 K=160 =================
    f32x4 acc2[2][4];
#pragma unroll
    for (int i = 0; i < 2; ++i)
#pragma unroll
        for (int j = 0; j < 4; ++j) acc2[i][j] = (f32x4){0.f, 0.f, 0.f, 0.f};

    const int wc2 = (wv >> 1) * 64;
    for (int kt = 0; kt < 5; ++kt) {
        const int k0 = kt * 32;
        // stage w2 128x32 -> bf16 (row stride 150 fp32 -> only 8B-aligned; use float2/scalar)
        for (int idx = t; idx < 512; idx += 256) {
            const int row = idx >> 2;
            const int ko  = (idx & 3) * 8;
            const int k   = k0 + ko;
            union { short8 s; __hip_bfloat16 h[8]; } u;
            if (k + 7 < HID) {
                const float* p = &w2[(size_t)row * HID + k];
#pragma unroll
                for (int j = 0; j < 4; ++j) {
                    const float2 f2 = *(const float2*)(p + 2 * j);
                    u.h[2 * j]     = __float2bfloat16(f2.x);
                    u.h[2 * j + 1] = __float2bfloat16(f2.y);
                }
            } else {
#pragma unroll
                for (int j = 0; j < 8; ++j)
                    u.h[j] = __float2bfloat16((k + j < HID) ? w2[(size_t)row * HID + k + j] : 0.f);
            }
            *(short8*)&Ws2[row * 40 + ko] = u.s;
        }
        __syncthreads();
        const short8 a0 = *(const short8*)&Hs[(wr + m16) * 168 + k0 + quad * 8];
        const short8 a1 = *(const short8*)&Hs[(wr + 16 + m16) * 168 + k0 + quad * 8];
#pragma unroll
        for (int tj = 0; tj < 4; ++tj) {
            const short8 b = *(const short8*)&Ws2[(wc2 + tj * 16 + m16) * 40 + quad * 8];
            acc2[0][tj] = __builtin_amdgcn_mfma_f32_16x16x32_bf16(a0, b, acc2[0][tj], 0, 0, 0);
            acc2[1][tj] = __builtin_amdgcn_mfma_f32_16x16x32_bf16(a1, b, acc2[1][tj], 0, 0, 0);
        }
        __syncthreads();
    }
    // epilogue 2 -> Ts fp32 (aliases staging+Hs; all Hs reads behind last barrier)
#pragma unroll
    for (int tj = 0; tj < 4; ++tj) {
        const int col = wc2 + tj * 16 + m16;
        const float bv = b2[col];
#pragma unroll
        for (int ti = 0; ti < 2; ++ti) {
#pragma unroll
            for (int r = 0; r < 4; ++r) {
                const int row = wr + ti * 16 + quad * 4 + r;
                Ts[row * 132 + col] = lrelu(acc2[ti][tj][r] + bv);
            }
        }
    }
    if (t < 40) S_lds[t] = 0.f;
    __syncthreads();

    // ================= Phase 3: features / logits / partial softmax =================
    {
        const int row = t >> 2;       // 0..63
        const int f   = t & 3;
        const int gr  = r0 + row;
        const int b   = gr / 5;
        const int n   = gr - b * 5;
        const int uid = batch[b * 6];
        const int iid = batch[b * 6 + 1 + n];
        const float* up  = user_table + (size_t)uid * DD + f * 32;
        const float* ip  = item_table + (size_t)iid * DD + f * 32;
        const float* tp  = Ts + row * 132 + f * 32;
        const float* a1p = aw1 + f * 2 * 96;   // [m][3*32]

        float ss = 0.f, z0 = 0.f, z1 = 0.f, sui = 0.f, sut = 0.f;
#pragma unroll
        for (int q = 0; q < 8; ++q) {
            const float4 u4 = *(const float4*)(up + q * 4);
            const float4 e4 = *(const float4*)(ip + q * 4);
            const float4 t4 = *(const float4*)(tp + q * 4);
            const float uu[4] = {u4.x, u4.y, u4.z, u4.w};
            const float ee[4] = {e4.x, e4.y, e4.z, e4.w};
            const float tt[4] = {t4.x, t4.y, t4.z, t4.w};
#pragma unroll
            for (int c = 0; c < 4; ++c) {
                const int i = q * 4 + c;
                const float u = uu[c], e = ee[c], x = tt[c];
                ss  = fmaf(u, u, ss); ss = fmaf(e, e, ss); ss = fmaf(x, x, ss);
                z0  = fmaf(u, a1p[i],       z0);
                z0  = fmaf(e, a1p[32 + i],  z0);
                z0  = fmaf(x, a1p[64 + i],  z0);
                z1  = fmaf(u, a1p[96 + i],  z1);
                z1  = fmaf(e, a1p[128 + i], z1);
                z1  = fmaf(x, a1p[160 + i], z1);
                sui = fmaf(u, e, sui);
                sut = fmaf(u, x, sut);
            }
        }
        const float inv = 1.f / fmaxf(sqrtf(ss), 1e-12f);
        const float h0 = tanhf(fmaf(z0, inv, ab1[f * 2 + 0]));
        const float h1 = tanhf(fmaf(z1, inv, ab1[f * 2 + 1]));
        const float l0 = fmaf(h0, aw2[f * 4 + 0], h1 * aw2[f * 4 + 1]);
        const float l1 = fmaf(h0, aw2[f * 4 + 2], h1 * aw2[f * 4 + 3]);
        const float e0 = expf(l0), e1 = expf(l1);
        const float pui = softplusf(sui), put = softplusf(sut);
        *(float4*)&expp[((size_t)gr * 4 + f) * 4] = make_float4(e0, e1, pui, put);
        atomicAdd(&S_lds[n * 8 + f * 2 + 0], e0);
        atomicAdd(&S_lds[n * 8 + f * 2 + 1], e1);
    }
    __syncthreads();
    if (t < 40) atomicAdd(&Sglob[t * 32], S_lds[t]);
}

__global__ void finalize(const float* __restrict__ expp,
                         const float* __restrict__ Sglob,
                         float* __restrict__ out)
{
    const int gr = blockIdx.x * 256 + threadIdx.x;
    if (gr >= ROWS) return;
    const int b = gr / 5;
    const int n = gr - b * 5;
    float r = 0.f;
#pragma unroll
    for (int f = 0; f < 4; ++f) {
        const float4 v = *(const float4*)&expp[((size_t)gr * 4 + f) * 4];
        const float S0 = Sglob[(n * 8 + f * 2 + 0) * 32];
        const float S1 = Sglob[(n * 8 + f * 2 + 1) * 32];
        r += v.x / S0 * v.z + v.y / S1 * v.w;
    }
    out[gr] = r;
}

extern "C" void kernel_launch(void* const* d_in, const int* in_sizes, int n_in,
                              void* d_out, int out_size, void* d_ws, size_t ws_size,
                              hipStream_t stream)
{
    (void)in_sizes; (void)n_in; (void)out_size; (void)ws_size;
    const int*   batch      = (const int*)d_in[0];
    const float* text       = (const float*)d_in[1];
    const float* user_table = (const float*)d_in[2];
    const float* item_table = (const float*)d_in[3];
    const float* w1         = (const float*)d_in[4];
    const float* b1         = (const float*)d_in[5];
    const float* w2         = (const float*)d_in[6];
    const float* b2         = (const float*)d_in[7];
    const float* aw1        = (const float*)d_in[8];
    const float* ab1        = (const float*)d_in[9];
    const float* aw2        = (const float*)d_in[10];
    float* out = (float*)d_out;

    float* expp  = (float*)d_ws;                  // ROWS*16 floats = 5.24 MB
    float* Sglob = expp + (size_t)ROWS * 16;      // 40*32 floats

    hipMemsetAsync(Sglob, 0, 40 * 32 * sizeof(float), stream);
    fused_main<<<ROWS / RT, 256, 0, stream>>>(batch, text, user_table, item_table,
                                              w1, b1, w2, b2, aw1, ab1, aw2,
                                              expp, Sglob);
    finalize<<<(ROWS + 255) / 256, 256, 0, stream>>>(expp, Sglob, out);
}

// Round 3
// 369.870 us; speedup vs baseline: 1.3959x; 1.0300x over previous
//
#include <hip/hip_runtime.h>
#include <hip/hip_bf16.h>

#define TDIM 384
#define HID 150
#define DD 128
#define ROWS 81920          // 16384 * 5
#define RT 64               // rows per block

typedef __attribute__((ext_vector_type(8))) short short8;
typedef __attribute__((ext_vector_type(4))) float f32x4;

// LDS byte map (aliased phases), K1:
//   GEMM1 loop : As [64][40]bf16 @0 (5120) | Ws1 [160][40]bf16 @5120 (12800)
//   GEMM2      : Hs [64][168]bf16 @0 (21504, aliases As+Ws1, written after last
//                GEMM1 barrier) | Ws2 [128][40]bf16 @21504 (10240)
#define AS_OFF   0
#define WS1_OFF  5120
#define HS_OFF   0
#define WS2_OFF  21504
#define SMEM_BYTES 31744

__device__ __forceinline__ float lrelu(float x) { return x > 0.f ? x : 0.01f * x; }
__device__ __forceinline__ float softplusf(float x) {
    return fmaxf(x, 0.f) + log1pf(expf(-fabsf(x)));
}

__device__ __forceinline__ short8 pack8(const float4 a, const float4 b) {
    union { short8 s; __hip_bfloat16 h[8]; } u;
    u.h[0] = __float2bfloat16(a.x); u.h[1] = __float2bfloat16(a.y);
    u.h[2] = __float2bfloat16(a.z); u.h[3] = __float2bfloat16(a.w);
    u.h[4] = __float2bfloat16(b.x); u.h[5] = __float2bfloat16(b.y);
    u.h[6] = __float2bfloat16(b.z); u.h[7] = __float2bfloat16(b.w);
    return u.s;
}

// =============== K1: te = leaky(leaky(text@w1^T+b1)@w2^T+b2) -> ws fp32 ===============
__global__ __launch_bounds__(256, 5)
void gemm_te(const float* __restrict__ text,
             const float* __restrict__ w1,
             const float* __restrict__ b1,
             const float* __restrict__ w2,
             const float* __restrict__ b2,
             float* __restrict__ te)
{
    __shared__ __align__(16) unsigned char smem[SMEM_BYTES];
    __hip_bfloat16* As  = (__hip_bfloat16*)(smem + AS_OFF);
    __hip_bfloat16* Ws1 = (__hip_bfloat16*)(smem + WS1_OFF);
    __hip_bfloat16* Hs  = (__hip_bfloat16*)(smem + HS_OFF);
    __hip_bfloat16* Ws2 = (__hip_bfloat16*)(smem + WS2_OFF);

    const int t    = threadIdx.x;
    const int r0   = blockIdx.x * RT;
    const int lane = t & 63;
    const int wv   = t >> 6;
    const int m16  = lane & 15;
    const int quad = lane >> 4;
    const int wr   = (wv & 1) * 32;
    const int wc   = (wv >> 1) * 80;   // GEMM1 col offset
    const int wc2  = (wv >> 1) * 64;   // GEMM2 col offset

    const int srow = t >> 2;           // 0..63
    const int sko  = (t & 3) * 8;      // k octet
    const bool hasx = (t < 128);       // 3rd W1 chunk holder

    // ---------------- GEMM1: M=64 N=160(150) K=384, BK=32, pipelined ----------------
    f32x4 acc1[2][5];
#pragma unroll
    for (int i = 0; i < 2; ++i)
#pragma unroll
        for (int j = 0; j < 5; ++j) acc1[i][j] = (f32x4){0.f, 0.f, 0.f, 0.f};

    float4 pa0, pa1;          // text prefetch
    float4 pw[3][2];          // w1 prefetch: rows srow, srow+64, srow+128(t<128)

    auto loadA = [&](int kt) {
        const float* p = &text[(size_t)(r0 + srow) * TDIM + kt * 32 + sko];
        pa0 = *(const float4*)p;
        pa1 = *(const float4*)(p + 4);
    };
    auto loadW1 = [&](int kt) {
#pragma unroll
        for (int h = 0; h < 3; ++h) {
            if (h == 2 && !hasx) continue;
            const int row = srow + 64 * h;
            if (row < HID) {
                const float* p = &w1[(size_t)row * TDIM + kt * 32 + sko];
                pw[h][0] = *(const float4*)p;
                pw[h][1] = *(const float4*)(p + 4);
            } else {
                pw[h][0] = make_float4(0.f, 0.f, 0.f, 0.f);
                pw[h][1] = make_float4(0.f, 0.f, 0.f, 0.f);
            }
        }
    };

    loadA(0);
    loadW1(0);
    for (int kt = 0; kt < 12; ++kt) {
        // commit prefetched tile to LDS
        *(short8*)&As[srow * 40 + sko] = pack8(pa0, pa1);
#pragma unroll
        for (int h = 0; h < 3; ++h) {
            if (h == 2 && !hasx) continue;
            const int row = srow + 64 * h;
            *(short8*)&Ws1[row * 40 + sko] = pack8(pw[h][0], pw[h][1]);
        }
        __syncthreads();
        if (kt < 11) { loadA(kt + 1); loadW1(kt + 1); }   // overlap with MFMA

        const short8 a0 = *(const short8*)&As[(wr + m16) * 40 + quad * 8];
        const short8 a1 = *(const short8*)&As[(wr + 16 + m16) * 40 + quad * 8];
#pragma unroll
        for (int tj = 0; tj < 5; ++tj) {
            const short8 b = *(const short8*)&Ws1[(wc + tj * 16 + m16) * 40 + quad * 8];
            acc1[0][tj] = __builtin_amdgcn_mfma_f32_16x16x32_bf16(a0, b, acc1[0][tj], 0, 0, 0);
            acc1[1][tj] = __builtin_amdgcn_mfma_f32_16x16x32_bf16(a1, b, acc1[1][tj], 0, 0, 0);
        }
        __syncthreads();
    }

    // prefetch first w2 tile while writing Hs (Ws2 region is disjoint)
    float pw2[2][8];
    auto loadW2 = [&](int kt) {
        const int k0 = kt * 32;
#pragma unroll
        for (int h = 0; h < 2; ++h) {
            const int row = srow + 64 * h + ((t >> 31) & 0);  // row = srow + h*64? no:
            (void)row;
        }
        // chunk idx = t + h*256 -> row = (idx>>2) = srow + 64h is wrong for W2 (128 rows):
        // W2 has 512 chunks: idx -> row = idx>>2 in [0,128), ko = (idx&3)*8
#pragma unroll
        for (int h = 0; h < 2; ++h) {
            const int idx = t + h * 256;
            const int row = idx >> 2;
            const int ko  = (idx & 3) * 8;
            const int k   = k0 + ko;
#pragma unroll
            for (int j = 0; j < 8; ++j)
                pw2[h][j] = (k + j < HID) ? w2[(size_t)row * HID + k + j] : 0.f;
        }
    };
    auto storeW2 = [&]() {
#pragma unroll
        for (int h = 0; h < 2; ++h) {
            const int idx = t + h * 256;
            const int row = idx >> 2;
            const int ko  = (idx & 3) * 8;
            union { short8 s; __hip_bfloat16 hb[8]; } u;
#pragma unroll
            for (int j = 0; j < 8; ++j) u.hb[j] = __float2bfloat16(pw2[h][j]);
            *(short8*)&Ws2[row * 40 + ko] = u.s;
        }
    };

    loadW2(0);

    // epilogue 1 -> Hs bf16 (C layout: col=lane&15, row=quad*4+reg); zero cols >=150
#pragma unroll
    for (int tj = 0; tj < 5; ++tj) {
        const int col = wc + tj * 16 + m16;
        const float bv = (col < HID) ? b1[col] : 0.f;
#pragma unroll
        for (int ti = 0; ti < 2; ++ti) {
#pragma unroll
            for (int r = 0; r < 4; ++r) {
                const int row = wr + ti * 16 + quad * 4 + r;
                float v = lrelu(acc1[ti][tj][r] + bv);
                if (col >= HID) v = 0.f;
                Hs[row * 168 + col] = __float2bfloat16(v);
            }
        }
    }
    storeW2();
    __syncthreads();

    // ---------------- GEMM2: M=64 N=128 K=160(150), BK=32, pipelined ----------------
    f32x4 acc2[2][4];
#pragma unroll
    for (int i = 0; i < 2; ++i)
#pragma unroll
        for (int j = 0; j < 4; ++j) acc2[i][j] = (f32x4){0.f, 0.f, 0.f, 0.f};

#pragma unroll
    for (int kt = 0; kt < 5; ++kt) {
        if (kt < 4) loadW2(kt + 1);
        const int k0 = kt * 32;
        const short8 a0 = *(const short8*)&Hs[(wr + m16) * 168 + k0 + quad * 8];
        const short8 a1 = *(const short8*)&Hs[(wr + 16 + m16) * 168 + k0 + quad * 8];
#pragma unroll
        for (int tj = 0; tj < 4; ++tj) {
            const short8 b = *(const short8*)&Ws2[(wc2 + tj * 16 + m16) * 40 + quad * 8];
            acc2[0][tj] = __builtin_amdgcn_mfma_f32_16x16x32_bf16(a0, b, acc2[0][tj], 0, 0, 0);
            acc2[1][tj] = __builtin_amdgcn_mfma_f32_16x16x32_bf16(a1, b, acc2[1][tj], 0, 0, 0);
        }
        __syncthreads();
        if (kt < 4) { storeW2(); __syncthreads(); }
    }

    // epilogue 2 -> te global fp32
#pragma unroll
    for (int tj = 0; tj < 4; ++tj) {
        const int col = wc2 + tj * 16 + m16;
        const float bv = b2[col];
#pragma unroll
        for (int ti = 0; ti < 2; ++ti) {
#pragma unroll
            for (int r = 0; r < 4; ++r) {
                const int row = wr + ti * 16 + quad * 4 + r;
                te[(size_t)(r0 + row) * DD + col] = lrelu(acc2[ti][tj][r] + bv);
            }
        }
    }
}

// =============== K3: gathers / norm / attention logits / partial softmax ===============
__global__ __launch_bounds__(256, 4)
void phase3(const int* __restrict__ batch,
            const float* __restrict__ user_table,
            const float* __restrict__ item_table,
            const float* __restrict__ te,
            const float* __restrict__ aw1,
            const float* __restrict__ ab1,
            const float* __restrict__ aw2,
            float* __restrict__ expp,
            float* __restrict__ Sglob)
{
    __shared__ float S_lds[40];
    const int t = threadIdx.x;
    if (t < 40) S_lds[t] = 0.f;
    __syncthreads();

    const int row = t >> 2;
    const int f   = t & 3;
    const int gr  = blockIdx.x * 64 + row;
    const int b   = gr / 5;
    const int n   = gr - b * 5;
    const int uid = batch[b * 6];
    const int iid = batch[b * 6 + 1 + n];
    const float* up  = user_table + (size_t)uid * DD + f * 32;
    const float* ip  = item_table + (size_t)iid * DD + f * 32;
    const float* tp  = te + (size_t)gr * DD + f * 32;
    const float* a1p = aw1 + f * 2 * 96;

    float ss = 0.f, z0 = 0.f, z1 = 0.f, sui = 0.f, sut = 0.f;
#pragma unroll
    for (int q = 0; q < 8; ++q) {
        const float4 u4 = *(const float4*)(up + q * 4);
        const float4 e4 = *(const float4*)(ip + q * 4);
        const float4 t4 = *(const float4*)(tp + q * 4);
        const float uu[4] = {u4.x, u4.y, u4.z, u4.w};
        const float ee[4] = {e4.x, e4.y, e4.z, e4.w};
        const float tt[4] = {t4.x, t4.y, t4.z, t4.w};
#pragma unroll
        for (int c = 0; c < 4; ++c) {
            const int i = q * 4 + c;
            const float u = uu[c], e = ee[c], x = tt[c];
            ss  = fmaf(u, u, ss); ss = fmaf(e, e, ss); ss = fmaf(x, x, ss);
            z0  = fmaf(u, a1p[i],       z0);
            z0  = fmaf(e, a1p[32 + i],  z0);
            z0  = fmaf(x, a1p[64 + i],  z0);
            z1  = fmaf(u, a1p[96 + i],  z1);
            z1  = fmaf(e, a1p[128 + i], z1);
            z1  = fmaf(x, a1p[160 + i], z1);
            sui = fmaf(u, e, sui);
            sut = fmaf(u, x, sut);
        }
    }
    const float inv = 1.f / fmaxf(sqrtf(ss), 1e-12f);
    const float h0 = tanhf(fmaf(z0, inv, ab1[f * 2 + 0]));
    const float h1 = tanhf(fmaf(z1, inv, ab1[f * 2 + 1]));
    const float l0 = fmaf(h0, aw2[f * 4 + 0], h1 * aw2[f * 4 + 1]);
    const float l1 = fmaf(h0, aw2[f * 4 + 2], h1 * aw2[f * 4 + 3]);
    const float e0 = expf(l0), e1 = expf(l1);
    const float pui = softplusf(sui), put = softplusf(sut);
    *(float4*)&expp[((size_t)gr * 4 + f) * 4] = make_float4(e0, e1, pui, put);
    atomicAdd(&S_lds[n * 8 + f * 2 + 0], e0);
    atomicAdd(&S_lds[n * 8 + f * 2 + 1], e1);
    __syncthreads();
    if (t < 40) atomicAdd(&Sglob[t * 32], S_lds[t]);
}

// =============== K4: ratings ===============
__global__ void finalize(const float* __restrict__ expp,
                         const float* __restrict__ Sglob,
                         float* __restrict__ out)
{
    const int gr = blockIdx.x * 256 + threadIdx.x;
    if (gr >= ROWS) return;
    const int b = gr / 5;
    const int n = gr - b * 5;
    float r = 0.f;
#pragma unroll
    for (int f = 0; f < 4; ++f) {
        const float4 v = *(const float4*)&expp[((size_t)gr * 4 + f) * 4];
        const float S0 = Sglob[(n * 8 + f * 2 + 0) * 32];
        const float S1 = Sglob[(n * 8 + f * 2 + 1) * 32];
        r += v.x / S0 * v.z + v.y / S1 * v.w;
    }
    out[gr] = r;
}

extern "C" void kernel_launch(void* const* d_in, const int* in_sizes, int n_in,
                              void* d_out, int out_size, void* d_ws, size_t ws_size,
                              hipStream_t stream)
{
    (void)in_sizes; (void)n_in; (void)out_size; (void)ws_size;
    const int*   batch      = (const int*)d_in[0];
    const float* text       = (const float*)d_in[1];
    const float* user_table = (const float*)d_in[2];
    const float* item_table = (const float*)d_in[3];
    const float* w1         = (const float*)d_in[4];
    const float* b1         = (const float*)d_in[5];
    const float* w2         = (const float*)d_in[6];
    const float* b2         = (const float*)d_in[7];
    const float* aw1        = (const float*)d_in[8];
    const float* ab1        = (const float*)d_in[9];
    const float* aw2        = (const float*)d_in[10];
    float* out = (float*)d_out;

    float* te    = (float*)d_ws;                   // ROWS*128 f32 = 41.9 MB
    float* expp  = te + (size_t)ROWS * DD;         // ROWS*16 f32 = 5.24 MB
    float* Sglob = expp + (size_t)ROWS * 16;       // 40*32 f32

    hipMemsetAsync(Sglob, 0, 40 * 32 * sizeof(float), stream);
    gemm_te<<<ROWS / RT, 256, 0, stream>>>(text, w1, b1, w2, b2, te);
    phase3<<<ROWS / 64, 256, 0, stream>>>(batch, user_table, item_table, te,
                                          aw1, ab1, aw2, expp, Sglob);
    finalize<<<(ROWS + 255) / 256, 256, 0, stream>>>(expp, Sglob, out);
}

// Round 4
// 356.497 us; speedup vs baseline: 1.4483x; 1.0375x over previous
//
#include <hip/hip_runtime.h>
#include <hip/hip_bf16.h>

#define TDIM 384
#define HID 150
#define DD 128
#define ROWS 81920          // 16384 * 5
#define RT 64               // rows per block

typedef __attribute__((ext_vector_type(8))) short short8;
typedef __attribute__((ext_vector_type(4))) float f32x4;

// LDS byte map (aliased phases):
//  GEMM1 (double-buffered): Asb p @ p*5120 (2x5120) | Ws1b p @ 10240+p*12800 (2x12800)  -> 35840
//  GEMM2: Hs [64][168]bf16 @0 (21504) | Ws2b p @ 21504+p*10240 (2x10240)                 -> 41984
//  Tail : Ts [64][132]f32 @0 (33792)
#define SMEM_BYTES 41984

__device__ __forceinline__ float lrelu(float x) { return x > 0.f ? x : 0.01f * x; }
__device__ __forceinline__ float softplusf(float x) {
    return fmaxf(x, 0.f) + log1pf(expf(-fabsf(x)));
}

__device__ __forceinline__ short8 pack8(const float4 a, const float4 b) {
    union { short8 s; __hip_bfloat16 h[8]; } u;
    u.h[0] = __float2bfloat16(a.x); u.h[1] = __float2bfloat16(a.y);
    u.h[2] = __float2bfloat16(a.z); u.h[3] = __float2bfloat16(a.w);
    u.h[4] = __float2bfloat16(b.x); u.h[5] = __float2bfloat16(b.y);
    u.h[6] = __float2bfloat16(b.z); u.h[7] = __float2bfloat16(b.w);
    return u.s;
}

__global__ __launch_bounds__(256, 3)
void fused_main(const int* __restrict__ batch,
                const float* __restrict__ text,
                const float* __restrict__ user_table,
                const float* __restrict__ item_table,
                const float* __restrict__ w1,
                const float* __restrict__ b1,
                const float* __restrict__ w2,
                const float* __restrict__ b2,
                const float* __restrict__ aw1,
                const float* __restrict__ ab1,
                const float* __restrict__ aw2,
                float* __restrict__ expp,   // [ROWS][4 f][4] = {e0,e1,p_ui,p_ut}
                float* __restrict__ Sglob)  // [40 * 32] padded accumulators
{
    __shared__ __align__(16) unsigned char smem[SMEM_BYTES];
    __shared__ float S_lds[40];
    __hip_bfloat16* Hs = (__hip_bfloat16*)(smem);
    float*          Ts = (float*)(smem);

    const int t    = threadIdx.x;
    const int r0   = blockIdx.x * RT;
    const int lane = t & 63;
    const int wv   = t >> 6;
    const int m16  = lane & 15;
    const int quad = lane >> 4;
    const int wr   = (wv & 1) * 32;
    const int wc   = (wv >> 1) * 80;   // GEMM1 col offset
    const int wc2  = (wv >> 1) * 64;   // GEMM2 col offset

    const int srow = t >> 2;           // 0..63
    const int sko  = (t & 3) * 8;      // k octet
    const bool hasx = (t < 128);

    // ---- phase-3 identity & index loads (issued immediately; resolve early) ----
    const int p3row = t >> 2;          // 0..63
    const int p3f   = t & 3;
    const int gr    = r0 + p3row;
    const int bb    = gr / 5;
    const int nn    = gr - bb * 5;
    const int uid   = batch[bb * 6];
    const int iid   = batch[bb * 6 + 1 + nn];

    if (t < 40) S_lds[t] = 0.f;

    // ================ GEMM1: M=64 N=160(150) K=384, BK=32, dbuf ================
    f32x4 acc1[2][5];
#pragma unroll
    for (int i = 0; i < 2; ++i)
#pragma unroll
        for (int j = 0; j < 5; ++j) acc1[i][j] = (f32x4){0.f, 0.f, 0.f, 0.f};

    float4 pa0, pa1;
    float4 pw[3][2];

    auto loadA = [&](int kt) {
        const float* p = &text[(size_t)(r0 + srow) * TDIM + kt * 32 + sko];
        pa0 = *(const float4*)p;
        pa1 = *(const float4*)(p + 4);
    };
    auto loadW1 = [&](int kt) {
#pragma unroll
        for (int h = 0; h < 3; ++h) {
            if (h == 2 && !hasx) continue;
            const int row = srow + 64 * h;
            if (row < HID) {
                const float* p = &w1[(size_t)row * TDIM + kt * 32 + sko];
                pw[h][0] = *(const float4*)p;
                pw[h][1] = *(const float4*)(p + 4);
            } else {
                pw[h][0] = make_float4(0.f, 0.f, 0.f, 0.f);
                pw[h][1] = make_float4(0.f, 0.f, 0.f, 0.f);
            }
        }
    };
    auto store1 = [&](int p) {
        __hip_bfloat16* As  = (__hip_bfloat16*)(smem + p * 5120);
        __hip_bfloat16* Ws1 = (__hip_bfloat16*)(smem + 10240 + p * 12800);
        *(short8*)&As[srow * 40 + sko] = pack8(pa0, pa1);
#pragma unroll
        for (int h = 0; h < 3; ++h) {
            if (h == 2 && !hasx) continue;
            *(short8*)&Ws1[(srow + 64 * h) * 40 + sko] = pack8(pw[h][0], pw[h][1]);
        }
    };

    loadA(0); loadW1(0);
    store1(0);
    __syncthreads();
    for (int kt = 0; kt < 12; ++kt) {
        if (kt < 11) { loadA(kt + 1); loadW1(kt + 1); }
        const int p = kt & 1;
        const __hip_bfloat16* As  = (const __hip_bfloat16*)(smem + p * 5120);
        const __hip_bfloat16* Ws1 = (const __hip_bfloat16*)(smem + 10240 + p * 12800);
        const short8 a0 = *(const short8*)&As[(wr + m16) * 40 + quad * 8];
        const short8 a1 = *(const short8*)&As[(wr + 16 + m16) * 40 + quad * 8];
#pragma unroll
        for (int tj = 0; tj < 5; ++tj) {
            const short8 b = *(const short8*)&Ws1[(wc + tj * 16 + m16) * 40 + quad * 8];
            acc1[0][tj] = __builtin_amdgcn_mfma_f32_16x16x32_bf16(a0, b, acc1[0][tj], 0, 0, 0);
            acc1[1][tj] = __builtin_amdgcn_mfma_f32_16x16x32_bf16(a1, b, acc1[1][tj], 0, 0, 0);
        }
        if (kt < 11) store1((kt + 1) & 1);   // other buffer: no extra barrier needed
        __syncthreads();
    }

    // ---- w2 tile-0 prefetch, then epilogue1 -> Hs ----
    float pw2[2][8];
    auto loadW2 = [&](int kt) {
        const int k0 = kt * 32;
#pragma unroll
        for (int h = 0; h < 2; ++h) {
            const int idx = t + h * 256;
            const int row = idx >> 2;
            const int ko  = (idx & 3) * 8;
            const int k   = k0 + ko;
#pragma unroll
            for (int j = 0; j < 8; ++j)
                pw2[h][j] = (k + j < HID) ? w2[(size_t)row * HID + k + j] : 0.f;
        }
    };
    auto store2 = [&](int p) {
        __hip_bfloat16* Ws2 = (__hip_bfloat16*)(smem + 21504 + p * 10240);
#pragma unroll
        for (int h = 0; h < 2; ++h) {
            const int idx = t + h * 256;
            const int row = idx >> 2;
            const int ko  = (idx & 3) * 8;
            union { short8 s; __hip_bfloat16 hb[8]; } u;
#pragma unroll
            for (int j = 0; j < 8; ++j) u.hb[j] = __float2bfloat16(pw2[h][j]);
            *(short8*)&Ws2[row * 40 + ko] = u.s;
        }
    };

    loadW2(0);

#pragma unroll
    for (int tj = 0; tj < 5; ++tj) {
        const int col = wc + tj * 16 + m16;
        const float bv = (col < HID) ? b1[col] : 0.f;
#pragma unroll
        for (int ti = 0; ti < 2; ++ti) {
#pragma unroll
            for (int r = 0; r < 4; ++r) {
                const int row = wr + ti * 16 + quad * 4 + r;
                float v = lrelu(acc1[ti][tj][r] + bv);
                if (col >= HID) v = 0.f;
                Hs[row * 168 + col] = __float2bfloat16(v);
            }
        }
    }
    store2(0);
    __syncthreads();

    // ---- issue u/ie gathers NOW; latency overlaps all of GEMM2 ----
    const float* up = user_table + (size_t)uid * DD + p3f * 32;
    const float* ip = item_table + (size_t)iid * DD + p3f * 32;
    float4 ur[8], er[8];
#pragma unroll
    for (int q = 0; q < 8; ++q) {
        ur[q] = *(const float4*)(up + q * 4);
        er[q] = *(const float4*)(ip + q * 4);
    }

    // ================ GEMM2: M=64 N=128 K=160(150), BK=32, dbuf ================
    f32x4 acc2[2][4];
#pragma unroll
    for (int i = 0; i < 2; ++i)
#pragma unroll
        for (int j = 0; j < 4; ++j) acc2[i][j] = (f32x4){0.f, 0.f, 0.f, 0.f};

#pragma unroll
    for (int kt = 0; kt < 5; ++kt) {
        if (kt < 4) loadW2(kt + 1);
        const int k0 = kt * 32;
        const __hip_bfloat16* Ws2 = (const __hip_bfloat16*)(smem + 21504 + (kt & 1) * 10240);
        const short8 a0 = *(const short8*)&Hs[(wr + m16) * 168 + k0 + quad * 8];
        const short8 a1 = *(const short8*)&Hs[(wr + 16 + m16) * 168 + k0 + quad * 8];
#pragma unroll
        for (int tj = 0; tj < 4; ++tj) {
            const short8 b = *(const short8*)&Ws2[(wc2 + tj * 16 + m16) * 40 + quad * 8];
            acc2[0][tj] = __builtin_amdgcn_mfma_f32_16x16x32_bf16(a0, b, acc2[0][tj], 0, 0, 0);
            acc2[1][tj] = __builtin_amdgcn_mfma_f32_16x16x32_bf16(a1, b, acc2[1][tj], 0, 0, 0);
        }
        if (kt < 4) store2((kt + 1) & 1);
        __syncthreads();
    }

    // ---- epilogue2 -> Ts fp32 in LDS (aliases Hs/Ws2; all reads behind barrier) ----
#pragma unroll
    for (int tj = 0; tj < 4; ++tj) {
        const int col = wc2 + tj * 16 + m16;
        const float bv = b2[col];
#pragma unroll
        for (int ti = 0; ti < 2; ++ti) {
#pragma unroll
            for (int r = 0; r < 4; ++r) {
                const int row = wr + ti * 16 + quad * 4 + r;
                Ts[row * 132 + col] = lrelu(acc2[ti][tj][r] + bv);
            }
        }
    }
    __syncthreads();

    // ================ Tail: norm / attention logits / partial softmax ================
    {
        const float* tp  = Ts + p3row * 132 + p3f * 32;
        const float* a1p = aw1 + p3f * 2 * 96;

        float ss = 0.f, z0 = 0.f, z1 = 0.f, sui = 0.f, sut = 0.f;
#pragma unroll
        for (int q = 0; q < 8; ++q) {
            const float4 u4 = ur[q];
            const float4 e4 = er[q];
            const float4 t4 = *(const float4*)(tp + q * 4);
            const float4 a00 = *(const float4*)(a1p + q * 4);
            const float4 a01 = *(const float4*)(a1p + 32 + q * 4);
            const float4 a02 = *(const float4*)(a1p + 64 + q * 4);
            const float4 a10 = *(const float4*)(a1p + 96 + q * 4);
            const float4 a11 = *(const float4*)(a1p + 128 + q * 4);
            const float4 a12 = *(const float4*)(a1p + 160 + q * 4);
            const float uu[4] = {u4.x, u4.y, u4.z, u4.w};
            const float ee[4] = {e4.x, e4.y, e4.z, e4.w};
            const float tt[4] = {t4.x, t4.y, t4.z, t4.w};
            const float w00[4] = {a00.x, a00.y, a00.z, a00.w};
            const float w01[4] = {a01.x, a01.y, a01.z, a01.w};
            const float w02[4] = {a02.x, a02.y, a02.z, a02.w};
            const float w10[4] = {a10.x, a10.y, a10.z, a10.w};
            const float w11[4] = {a11.x, a11.y, a11.z, a11.w};
            const float w12[4] = {a12.x, a12.y, a12.z, a12.w};
#pragma unroll
            for (int c = 0; c < 4; ++c) {
                const float u = uu[c], e = ee[c], x = tt[c];
                ss  = fmaf(u, u, ss); ss = fmaf(e, e, ss); ss = fmaf(x, x, ss);
                z0  = fmaf(u, w00[c], z0);
                z0  = fmaf(e, w01[c], z0);
                z0  = fmaf(x, w02[c], z0);
                z1  = fmaf(u, w10[c], z1);
                z1  = fmaf(e, w11[c], z1);
                z1  = fmaf(x, w12[c], z1);
                sui = fmaf(u, e, sui);
                sut = fmaf(u, x, sut);
            }
        }
        const float inv = 1.f / fmaxf(sqrtf(ss), 1e-12f);
        const float h0 = tanhf(fmaf(z0, inv, ab1[p3f * 2 + 0]));
        const float h1 = tanhf(fmaf(z1, inv, ab1[p3f * 2 + 1]));
        const float l0 = fmaf(h0, aw2[p3f * 4 + 0], h1 * aw2[p3f * 4 + 1]);
        const float l1 = fmaf(h0, aw2[p3f * 4 + 2], h1 * aw2[p3f * 4 + 3]);
        const float e0 = expf(l0), e1 = expf(l1);
        const float pui = softplusf(sui), put = softplusf(sut);
        *(float4*)&expp[((size_t)gr * 4 + p3f) * 4] = make_float4(e0, e1, pui, put);
        atomicAdd(&S_lds[nn * 8 + p3f * 2 + 0], e0);
        atomicAdd(&S_lds[nn * 8 + p3f * 2 + 1], e1);
    }
    __syncthreads();
    if (t < 40) atomicAdd(&Sglob[t * 32], S_lds[t]);
}

// =============== K2: ratings ===============
__global__ void finalize(const float* __restrict__ expp,
                         const float* __restrict__ Sglob,
                         float* __restrict__ out)
{
    const int gr = blockIdx.x * 256 + threadIdx.x;
    if (gr >= ROWS) return;
    const int b = gr / 5;
    const int n = gr - b * 5;
    float r = 0.f;
#pragma unroll
    for (int f = 0; f < 4; ++f) {
        const float4 v = *(const float4*)&expp[((size_t)gr * 4 + f) * 4];
        const float S0 = Sglob[(n * 8 + f * 2 + 0) * 32];
        const float S1 = Sglob[(n * 8 + f * 2 + 1) * 32];
        r += v.x / S0 * v.z + v.y / S1 * v.w;
    }
    out[gr] = r;
}

extern "C" void kernel_launch(void* const* d_in, const int* in_sizes, int n_in,
                              void* d_out, int out_size, void* d_ws, size_t ws_size,
                              hipStream_t stream)
{
    (void)in_sizes; (void)n_in; (void)out_size; (void)ws_size;
    const int*   batch      = (const int*)d_in[0];
    const float* text       = (const float*)d_in[1];
    const float* user_table = (const float*)d_in[2];
    const float* item_table = (const float*)d_in[3];
    const float* w1         = (const float*)d_in[4];
    const float* b1         = (const float*)d_in[5];
    const float* w2         = (const float*)d_in[6];
    const float* b2         = (const float*)d_in[7];
    const float* aw1        = (const float*)d_in[8];
    const float* ab1        = (const float*)d_in[9];
    const float* aw2        = (const float*)d_in[10];
    float* out = (float*)d_out;

    float* expp  = (float*)d_ws;                   // ROWS*16 f32 = 5.24 MB
    float* Sglob = expp + (size_t)ROWS * 16;       // 40*32 f32

    hipMemsetAsync(Sglob, 0, 40 * 32 * sizeof(float), stream);
    fused_main<<<ROWS / RT, 256, 0, stream>>>(batch, text, user_table, item_table,
                                              w1, b1, w2, b2, aw1, ab1, aw2,
                                              expp, Sglob);
    finalize<<<(ROWS + 255) / 256, 256, 0, stream>>>(expp, Sglob, out);
}

// Round 7
// 344.033 us; speedup vs baseline: 1.5007x; 1.0362x over previous
//
#include <hip/hip_runtime.h>
#include <hip/hip_bf16.h>

#define TDIM 384
#define HID 150
#define DD 128
#define ROWS 81920          // 16384 * 5
#define RT 64               // rows per block

typedef __attribute__((ext_vector_type(8))) short short8;
typedef __attribute__((ext_vector_type(4))) float f32x4;

// LDS byte map (aliased phases):
//  GEMM1: As0@0(5120) As1@5120(5120) | Ws1_0@10240(12800) Ws1_1@23040(12800) -> 35840
//  GEMM2: Hs[64][168]bf16 @0 (21504) | Ws2 @21504 (10240) -> 31744
//  Tail : Ts[64][132]f32 @0 (33792)
#define SMEM_BYTES 35840

__device__ __forceinline__ float lrelu(float x) { return x > 0.f ? x : 0.01f * x; }
__device__ __forceinline__ float softplusf(float x) {
    return fmaxf(x, 0.f) + log1pf(expf(-fabsf(x)));
}

__device__ __forceinline__ short8 pack8(const float4 a, const float4 b) {
    union { short8 s; __hip_bfloat16 h[8]; } u;
    u.h[0] = __float2bfloat16(a.x); u.h[1] = __float2bfloat16(a.y);
    u.h[2] = __float2bfloat16(a.z); u.h[3] = __float2bfloat16(a.w);
    u.h[4] = __float2bfloat16(b.x); u.h[5] = __float2bfloat16(b.y);
    u.h[6] = __float2bfloat16(b.z); u.h[7] = __float2bfloat16(b.w);
    return u.s;
}

// =============== K0: prepack w1/w2 -> bf16 fragment-tile order ===============
__global__ __launch_bounds__(256)
void prep_w(const float* __restrict__ w1, const float* __restrict__ w2,
            short8* __restrict__ w1f, short8* __restrict__ w2f)
{
    const int idx = blockIdx.x * 256 + threadIdx.x;
    union { short8 s; __hip_bfloat16 h[8]; } u;
    if (idx < 7680) {
        const int kt = idx / 640, c = idx % 640;
        const int col = c >> 2, q = c & 3;
        const int k = kt * 32 + q * 8;
#pragma unroll
        for (int j = 0; j < 8; ++j)
            u.h[j] = __float2bfloat16(col < HID ? w1[(size_t)col * TDIM + k + j] : 0.f);
        w1f[idx] = u.s;
    } else if (idx < 10240) {
        const int i2 = idx - 7680;
        const int kt = i2 / 512, c = i2 % 512;
        const int col = c >> 2, q = c & 3;
        const int k = kt * 32 + q * 8;
#pragma unroll
        for (int j = 0; j < 8; ++j)
            u.h[j] = __float2bfloat16((k + j) < HID ? w2[(size_t)col * HID + k + j] : 0.f);
        w2f[i2] = u.s;
    }
}

// =============== K1: fused GEMM1+GEMM2+tail ===============
__global__ __launch_bounds__(256, 4)
void fused_main(const int* __restrict__ batch,
                const float* __restrict__ text,
                const float* __restrict__ user_table,
                const float* __restrict__ item_table,
                const short8* __restrict__ w1f,
                const float* __restrict__ b1,
                const short8* __restrict__ w2f,
                const float* __restrict__ b2,
                const float* __restrict__ aw1,
                const float* __restrict__ ab1,
                const float* __restrict__ aw2,
                float* __restrict__ expp,
                float* __restrict__ Sglob)
{
    __shared__ __align__(16) unsigned char smem[SMEM_BYTES];
    __shared__ float S_lds[40];
    __hip_bfloat16* Hs = (__hip_bfloat16*)(smem);
    float*          Ts = (float*)(smem);

    const int t    = threadIdx.x;
    const int r0   = blockIdx.x * RT;
    const int lane = t & 63;
    const int wv   = t >> 6;
    const int m16  = lane & 15;
    const int quad = lane >> 4;
    const int wr   = (wv & 1) * 32;
    const int wc   = (wv >> 1) * 80;
    const int wc2  = (wv >> 1) * 64;

    const int srow = t >> 2;
    const int sko  = (t & 3) * 8;
    const bool hasx = (t < 128);

    const int p3row = t >> 2;
    const int p3f   = t & 3;
    const int gr    = r0 + p3row;
    const int bb    = gr / 5;
    const int nn    = gr - bb * 5;
    const int uid   = batch[bb * 6];
    const int iid   = batch[bb * 6 + 1 + nn];

    if (t < 40) S_lds[t] = 0.f;

    // ---------------- GEMM1: M=64 N=160(150) K=384, BK=32, dbuf ----------------
    f32x4 acc1[2][5];
#pragma unroll
    for (int i = 0; i < 2; ++i)
#pragma unroll
        for (int j = 0; j < 5; ++j) acc1[i][j] = (f32x4){0.f, 0.f, 0.f, 0.f};

    float4 pa0a, pa0b, pa1a, pa1b;
    short8 wr1a, wr1b, wr1c;

    const float* textp = &text[(size_t)(r0 + srow) * TDIM + sko];

    pa0a = *(const float4*)(textp);
    pa0b = *(const float4*)(textp + 4);
    wr1a = w1f[t];
    wr1b = w1f[t + 256];
    if (hasx) wr1c = w1f[t + 512];
    {
        __hip_bfloat16* As  = (__hip_bfloat16*)(smem);
        __hip_bfloat16* Ws1 = (__hip_bfloat16*)(smem + 10240);
        *(short8*)&As[srow * 40 + sko] = pack8(pa0a, pa0b);
        *(short8*)&Ws1[(t >> 2) * 40 + (t & 3) * 8] = wr1a;
        {
            const int c = t + 256;
            *(short8*)&Ws1[(c >> 2) * 40 + (c & 3) * 8] = wr1b;
        }
        if (hasx) {
            const int c = t + 512;
            *(short8*)&Ws1[(c >> 2) * 40 + (c & 3) * 8] = wr1c;
        }
    }
    pa1a = *(const float4*)(textp + 32);
    pa1b = *(const float4*)(textp + 36);
    __syncthreads();

#pragma unroll
    for (int kt = 0; kt < 12; ++kt) {
        const int p = kt & 1;
        if (kt < 10) {
            if (p == 0) {
                pa0a = *(const float4*)(textp + (kt + 2) * 32);
                pa0b = *(const float4*)(textp + (kt + 2) * 32 + 4);
            } else {
                pa1a = *(const float4*)(textp + (kt + 2) * 32);
                pa1b = *(const float4*)(textp + (kt + 2) * 32 + 4);
            }
        }
        if (kt < 11) {
            wr1a = w1f[(kt + 1) * 640 + t];
            wr1b = w1f[(kt + 1) * 640 + t + 256];
            if (hasx) wr1c = w1f[(kt + 1) * 640 + t + 512];
        }
        const __hip_bfloat16* As  = (const __hip_bfloat16*)(smem + p * 5120);
        const __hip_bfloat16* Ws1 = (const __hip_bfloat16*)(smem + 10240 + p * 12800);
        const short8 a0 = *(const short8*)&As[(wr + m16) * 40 + quad * 8];
        const short8 a1 = *(const short8*)&As[(wr + 16 + m16) * 40 + quad * 8];
#pragma unroll
        for (int tj = 0; tj < 5; ++tj) {
            const short8 b = *(const short8*)&Ws1[(wc + tj * 16 + m16) * 40 + quad * 8];
            acc1[0][tj] = __builtin_amdgcn_mfma_f32_16x16x32_bf16(a0, b, acc1[0][tj], 0, 0, 0);
            acc1[1][tj] = __builtin_amdgcn_mfma_f32_16x16x32_bf16(a1, b, acc1[1][tj], 0, 0, 0);
        }
        if (kt < 11) {
            __hip_bfloat16* Asn  = (__hip_bfloat16*)(smem + (p ^ 1) * 5120);
            __hip_bfloat16* Ws1n = (__hip_bfloat16*)(smem + 10240 + (p ^ 1) * 12800);
            *(short8*)&Asn[srow * 40 + sko] = (p == 0) ? pack8(pa1a, pa1b)
                                                       : pack8(pa0a, pa0b);
            *(short8*)&Ws1n[(t >> 2) * 40 + (t & 3) * 8] = wr1a;
            {
                const int c = t + 256;
                *(short8*)&Ws1n[(c >> 2) * 40 + (c & 3) * 8] = wr1b;
            }
            if (hasx) {
                const int c = t + 512;
                *(short8*)&Ws1n[(c >> 2) * 40 + (c & 3) * 8] = wr1c;
            }
        }
        __syncthreads();
    }

    // ---------------- epilogue1 -> Hs bf16 ----------------
    short8 wr2a = w2f[t];
    short8 wr2b = w2f[t + 256];

#pragma unroll
    for (int tj = 0; tj < 5; ++tj) {
        const int col = wc + tj * 16 + m16;
        const float bv = (col < HID) ? b1[col] : 0.f;
#pragma unroll
        for (int ti = 0; ti < 2; ++ti) {
#pragma unroll
            for (int r = 0; r < 4; ++r) {
                const int row = wr + ti * 16 + quad * 4 + r;
                float v = lrelu(acc1[ti][tj][r] + bv);
                if (col >= HID) v = 0.f;
                Hs[row * 168 + col] = __float2bfloat16(v);
            }
        }
    }
    __syncthreads();

    // ---------------- GEMM2: M=64 N=128 K=160(150), BK=32, single-buffer ----------------
    f32x4 acc2[2][4];
#pragma unroll
    for (int i = 0; i < 2; ++i)
#pragma unroll
        for (int j = 0; j < 4; ++j) acc2[i][j] = (f32x4){0.f, 0.f, 0.f, 0.f};

#pragma unroll
    for (int kt = 0; kt < 5; ++kt) {
        {
            __hip_bfloat16* Ws2 = (__hip_bfloat16*)(smem + 21504);
            *(short8*)&Ws2[(t >> 2) * 40 + (t & 3) * 8] = wr2a;
            const int c = t + 256;
            *(short8*)&Ws2[(c >> 2) * 40 + (c & 3) * 8] = wr2b;
        }
        __syncthreads();
        if (kt < 4) {
            wr2a = w2f[(kt + 1) * 512 + t];
            wr2b = w2f[(kt + 1) * 512 + t + 256];
        }
        const int k0 = kt * 32;
        const __hip_bfloat16* Ws2 = (const __hip_bfloat16*)(smem + 21504);
        const short8 a0 = *(const short8*)&Hs[(wr + m16) * 168 + k0 + quad * 8];
        const short8 a1 = *(const short8*)&Hs[(wr + 16 + m16) * 168 + k0 + quad * 8];
#pragma unroll
        for (int tj = 0; tj < 4; ++tj) {
            const short8 b = *(const short8*)&Ws2[(wc2 + tj * 16 + m16) * 40 + quad * 8];
            acc2[0][tj] = __builtin_amdgcn_mfma_f32_16x16x32_bf16(a0, b, acc2[0][tj], 0, 0, 0);
            acc2[1][tj] = __builtin_amdgcn_mfma_f32_16x16x32_bf16(a1, b, acc2[1][tj], 0, 0, 0);
        }
        __syncthreads();
    }

    // ---- issue gathers ----
    const float* up = user_table + (size_t)uid * DD + p3f * 32;
    const float* ip = item_table + (size_t)iid * DD + p3f * 32;
    float4 ur[8], er[8];
#pragma unroll
    for (int q = 0; q < 8; ++q) {
        ur[q] = *(const float4*)(up + q * 4);
        er[q] = *(const float4*)(ip + q * 4);
    }

    // ---- epilogue2 -> Ts fp32 in LDS ----
#pragma unroll
    for (int tj = 0; tj < 4; ++tj) {
        const int col = wc2 + tj * 16 + m16;
        const float bv = b2[col];
#pragma unroll
        for (int ti = 0; ti < 2; ++ti) {
#pragma unroll
            for (int r = 0; r < 4; ++r) {
                const int row = wr + ti * 16 + quad * 4 + r;
                Ts[row * 132 + col] = lrelu(acc2[ti][tj][r] + bv);
            }
        }
    }
    __syncthreads();

    // ---------------- Tail ----------------
    {
        const float* tp  = Ts + p3row * 132 + p3f * 32;
        const float* a1p = aw1 + p3f * 2 * 96;

        float ss = 0.f, z0 = 0.f, z1 = 0.f, sui = 0.f, sut = 0.f;
#pragma unroll
        for (int q = 0; q < 8; ++q) {
            const float4 u4 = ur[q];
            const float4 e4 = er[q];
            const float4 t4 = *(const float4*)(tp + q * 4);
            const float4 a00 = *(const float4*)(a1p + q * 4);
            const float4 a01 = *(const float4*)(a1p + 32 + q * 4);
            const float4 a02 = *(const float4*)(a1p + 64 + q * 4);
            const float4 a10 = *(const float4*)(a1p + 96 + q * 4);
            const float4 a11 = *(const float4*)(a1p + 128 + q * 4);
            const float4 a12 = *(const float4*)(a1p + 160 + q * 4);
            const float uu[4] = {u4.x, u4.y, u4.z, u4.w};
            const float ee[4] = {e4.x, e4.y, e4.z, e4.w};
            const float tt[4] = {t4.x, t4.y, t4.z, t4.w};
            const float w00[4] = {a00.x, a00.y, a00.z, a00.w};
            const float w01[4] = {a01.x, a01.y, a01.z, a01.w};
            const float w02[4] = {a02.x, a02.y, a02.z, a02.w};
            const float w10[4] = {a10.x, a10.y, a10.z, a10.w};
            const float w11[4] = {a11.x, a11.y, a11.z, a11.w};
            const float w12[4] = {a12.x, a12.y, a12.z, a12.w};
#pragma unroll
            for (int c = 0; c < 4; ++c) {
                const float u = uu[c], e = ee[c], x = tt[c];
                ss  = fmaf(u, u, ss); ss = fmaf(e, e, ss); ss = fmaf(x, x, ss);
                z0  = fmaf(u, w00[c], z0);
                z0  = fmaf(e, w01[c], z0);
                z0  = fmaf(x, w02[c], z0);
                z1  = fmaf(u, w10[c], z1);
                z1  = fmaf(e, w11[c], z1);
                z1  = fmaf(x, w12[c], z1);
                sui = fmaf(u, e, sui);
                sut = fmaf(u, x, sut);
            }
        }
        const float inv = 1.f / fmaxf(sqrtf(ss), 1e-12f);
        const float h0 = tanhf(fmaf(z0, inv, ab1[p3f * 2 + 0]));
        const float h1 = tanhf(fmaf(z1, inv, ab1[p3f * 2 + 1]));
        const float l0 = fmaf(h0, aw2[p3f * 4 + 0], h1 * aw2[p3f * 4 + 1]);
        const float l1 = fmaf(h0, aw2[p3f * 4 + 2], h1 * aw2[p3f * 4 + 3]);
        const float e0 = expf(l0), e1 = expf(l1);
        const float pui = softplusf(sui), put = softplusf(sut);
        *(float4*)&expp[((size_t)gr * 4 + p3f) * 4] = make_float4(e0, e1, pui, put);
        atomicAdd(&S_lds[nn * 8 + p3f * 2 + 0], e0);
        atomicAdd(&S_lds[nn * 8 + p3f * 2 + 1], e1);
    }
    __syncthreads();
    if (t < 40) atomicAdd(&Sglob[t * 32], S_lds[t]);
}

// =============== K2: ratings ===============
__global__ void finalize(const float* __restrict__ expp,
                         const float* __restrict__ Sglob,
                         float* __restrict__ out)
{
    const int gr = blockIdx.x * 256 + threadIdx.x;
    if (gr >= ROWS) return;
    const int b = gr / 5;
    const int n = gr - b * 5;
    float r = 0.f;
#pragma unroll
    for (int f = 0; f < 4; ++f) {
        const float4 v = *(const float4*)&expp[((size_t)gr * 4 + f) * 4];
        const float S0 = Sglob[(n * 8 + f * 2 + 0) * 32];
        const float S1 = Sglob[(n * 8 + f * 2 + 1) * 32];
        r += v.x / S0 * v.z + v.y / S1 * v.w;
    }
    out[gr] = r;
}

extern "C" void kernel_launch(void* const* d_in, const int* in_sizes, int n_in,
                              void* d_out, int out_size, void* d_ws, size_t ws_size,
                              hipStream_t stream)
{
    (void)in_sizes; (void)n_in; (void)out_size; (void)ws_size;
    const int*   batch      = (const int*)d_in[0];
    const float* text       = (const float*)d_in[1];
    const float* user_table = (const float*)d_in[2];
    const float* item_table = (const float*)d_in[3];
    const float* w1         = (const float*)d_in[4];
    const float* b1         = (const float*)d_in[5];
    const float* w2         = (const float*)d_in[6];
    const float* b2         = (const float*)d_in[7];
    const float* aw1        = (const float*)d_in[8];
    const float* ab1        = (const float*)d_in[9];
    const float* aw2        = (const float*)d_in[10];
    float* out = (float*)d_out;

    char* ws = (char*)d_ws;
    short8* w1f   = (short8*)ws;                        // 7680*16  = 122880 B
    short8* w2f   = (short8*)(ws + 122880);             // 2560*16  =  40960 B
    float*  expp  = (float*)(ws + 163840);              // ROWS*16 f32 = 5.24 MB
    float*  Sglob = (float*)(ws + 163840 + (size_t)ROWS * 16 * 4);

    hipMemsetAsync(Sglob, 0, 40 * 32 * sizeof(float), stream);
    prep_w<<<40, 256, 0, stream>>>(w1, w2, w1f, w2f);
    fused_main<<<ROWS / RT, 256, 0, stream>>>(batch, text, user_table, item_table,
                                              w1f, b1, w2f, b2, aw1, ab1, aw2,
                                              expp, Sglob);
    finalize<<<(ROWS + 255) / 256, 256, 0, stream>>>(expp, Sglob, out);
}